// Round 3
// baseline (233.744 us; speedup 1.0000x reference)
//
#include <hip/hip_runtime.h>

#define NPG 1024
#define NG 64
#define KKEEP 512
#define DF 256
#define NTOT (NG * NPG)        // 65536 nodes
#define NROWS (NG * KKEEP)     // 32768 kept rows
#define HI_ROWS 256
#define LO_ROWS (NROWS - HI_ROWS)  // 32512

__global__ void k_init(int* degc, long long* gcnq, int* node_map, int n) {
    int i = blockIdx.x * blockDim.x + threadIdx.x;
    if (i < n) { degc[i] = 0; gcnq[i] = 0; node_map[i] = -1; }
}

// one wave per node: dot(x, w1) and dot(x, wg), f64 accumulate
__global__ void k_dots(const float* __restrict__ x, const float* __restrict__ w1,
                       const float* __restrict__ wg, float* __restrict__ sc0,
                       float* __restrict__ xwg) {
    int node = blockIdx.x * 4 + (threadIdx.x >> 6);
    int lane = threadIdx.x & 63;
    const float4 xv = *reinterpret_cast<const float4*>(x + (size_t)node * DF + lane * 4);
    const float4 av = *reinterpret_cast<const float4*>(w1 + lane * 4);
    const float4 bv = *reinterpret_cast<const float4*>(wg + lane * 4);
    double s1 = (double)xv.x * av.x + (double)xv.y * av.y + (double)xv.z * av.z + (double)xv.w * av.w;
    double s2 = (double)xv.x * bv.x + (double)xv.y * bv.y + (double)xv.z * bv.z + (double)xv.w * bv.w;
#pragma unroll
    for (int off = 32; off; off >>= 1) {
        s1 += __shfl_xor(s1, off);
        s2 += __shfl_xor(s2, off);
    }
    if (lane == 0) { sc0[node] = (float)s1; xwg[node] = (float)s2; }
}

__global__ void k_deg(const int* __restrict__ rows, const int* __restrict__ cols,
                      int* __restrict__ degc, int E) {
    int e = blockIdx.x * blockDim.x + threadIdx.x;
    if (e >= E) return;
    int r = rows[e] & (NTOT - 1), c = cols[e] & (NTOT - 1);
    if (r != c) atomicAdd(&degc[c], 1);
}

// scatter: gcn[c] += dis[r]*dis[c]*xwg[r], fixed-point (2^-40) int64 atomics -> deterministic
__global__ void k_gcn(const int* __restrict__ rows, const int* __restrict__ cols,
                      const int* __restrict__ degc, const float* __restrict__ xwg,
                      long long* __restrict__ gcnq, int E) {
    int e = blockIdx.x * blockDim.x + threadIdx.x;
    if (e >= E) return;
    int r = rows[e] & (NTOT - 1), c = cols[e] & (NTOT - 1);
    if (r == c) return;
    int dr = degc[r], dc = degc[c];
    float disr = (dr > 0) ? (1.0f / sqrtf((float)dr)) : 0.0f;
    float disc = (dc > 0) ? (1.0f / sqrtf((float)dc)) : 0.0f;
    float term = disr * disc * xwg[r];
    long long q = (long long)llrint((double)term * 1099511627776.0);
    atomicAdd(reinterpret_cast<unsigned long long*>(&gcnq[c]), (unsigned long long)q);
}

__global__ void k_score(const float* __restrict__ sc0, const long long* __restrict__ gcnq,
                        const float* __restrict__ b1, const float* __restrict__ bg,
                        float* __restrict__ score, int n) {
    int i = blockIdx.x * blockDim.x + threadIdx.x;
    if (i >= n) return;
    float s1 = sc0[i] + b1[0];
    float s2 = (float)((double)gcnq[i] * (1.0 / 1099511627776.0)) + bg[0];
    score[i] = 0.5f * s1 + 0.5f * s2;
}

// per-graph: bitonic sort 1024 keys desc (score desc, index asc on ties), keep top 512
__global__ __launch_bounds__(512) void k_topk(const float* __restrict__ score,
                                              int* __restrict__ perm, int* __restrict__ node_map) {
    __shared__ unsigned long long keys[NPG];
    const int g = blockIdx.x;
    const int tid = threadIdx.x;
    const int base = g * NPG;
    for (int t = tid; t < NPG; t += 512) {
        float s = score[base + t];
        unsigned u = __float_as_uint(s);
        u = (u & 0x80000000u) ? ~u : (u | 0x80000000u);
        keys[t] = ((unsigned long long)u << 32) | (unsigned long long)(0xFFFFFFFFu - (unsigned)t);
    }
    __syncthreads();
    for (int k = 2; k <= NPG; k <<= 1) {
        for (int j = k >> 1; j > 0; j >>= 1) {
            for (int t = tid; t < NPG; t += 512) {
                int ixj = t ^ j;
                if (ixj > t) {
                    unsigned long long a = keys[t], b = keys[ixj];
                    bool desc = ((t & k) == 0);
                    if (desc ? (a < b) : (a > b)) { keys[t] = b; keys[ixj] = a; }
                }
            }
            __syncthreads();
        }
    }
    if (tid < KKEEP) {
        unsigned long long key = keys[tid];
        int idx = (int)(0xFFFFFFFFu - (unsigned)(key & 0xFFFFFFFFull)) & (NPG - 1);
        int gi = base + idx;
        perm[g * KKEEP + tid] = gi;
        node_map[gi] = g * KKEEP + tid;
    }
}

// pack {perm[row], tanh(score[perm[row]])} into rowinfo (tail of x_new region)
__global__ void k_prep(const float* __restrict__ score, const int* __restrict__ perm,
                       int2* __restrict__ rowinfo) {
    int r = blockIdx.x * blockDim.x + threadIdx.x;
    int p = perm[r] & (NTOT - 1);
    float tg = tanhf(score[p]);
    rowinfo[r] = make_int2(p, __float_as_int(tg));
}

__global__ void k_edges(const int* __restrict__ rows, const int* __restrict__ cols,
                        const int* __restrict__ node_map, float* __restrict__ oute, int E) {
    int e = blockIdx.x * blockDim.x + threadIdx.x;
    if (e >= E) return;
    int er = node_map[rows[e] & (NTOT - 1)];
    int ec = node_map[cols[e] & (NTOT - 1)];
    bool v = (er >= 0) && (ec >= 0);
    oute[e] = v ? (float)er : -1.0f;
    oute[(size_t)E + e] = v ? (float)ec : -1.0f;
}

// rows 0..32511: reads rowinfo (tail region, disjoint from written rows)
__global__ void k_gather_lo(const float* __restrict__ x, const int2* __restrict__ rowinfo,
                            float* __restrict__ outx, float* __restrict__ outb) {
    int row = blockIdx.x * 4 + (threadIdx.x >> 6);
    int lane = threadIdx.x & 63;
    int2 ri = rowinfo[row];
    float tg = __int_as_float(ri.y);
    const float4 v = *reinterpret_cast<const float4*>(x + (size_t)(ri.x & (NTOT - 1)) * DF + lane * 4);
    float4 o;
    o.x = v.x * tg; o.y = v.y * tg; o.z = v.z * tg; o.w = v.w * tg;
    *reinterpret_cast<float4*>(outx + (size_t)row * DF + lane * 4) = o;
    if (lane == 0) outb[row] = (float)(row >> 9);
}

// rows 32512..32767: single workgroup; stage rowinfo in LDS before overwriting its region
__global__ __launch_bounds__(1024) void k_gather_hi(const float* __restrict__ x,
                                                    const int2* __restrict__ rowinfo,
                                                    float* __restrict__ outx,
                                                    float* __restrict__ outb) {
    __shared__ int2 info[HI_ROWS];
    int tid = threadIdx.x;
    if (tid < HI_ROWS) info[tid] = rowinfo[LO_ROWS + tid];
    __syncthreads();
    for (int it = tid; it < HI_ROWS * 64; it += 1024) {
        int rl = it >> 6, lane = it & 63;
        int row = LO_ROWS + rl;
        int2 ri = info[rl];
        float tg = __int_as_float(ri.y);
        const float4 v = *reinterpret_cast<const float4*>(x + (size_t)(ri.x & (NTOT - 1)) * DF + lane * 4);
        float4 o;
        o.x = v.x * tg; o.y = v.y * tg; o.z = v.z * tg; o.w = v.w * tg;
        *reinterpret_cast<float4*>(outx + (size_t)row * DF + lane * 4) = o;
        if (lane == 0) outb[row] = (float)(row >> 9);
    }
}

extern "C" void kernel_launch(void* const* d_in, const int* in_sizes, int n_in,
                              void* d_out, int out_size, void* d_ws, size_t ws_size,
                              hipStream_t stream) {
    const float* x = (const float*)d_in[0];
    const int* ei = (const int*)d_in[1];
    const float* w1 = (const float*)d_in[3];
    const float* b1 = (const float*)d_in[4];
    const float* wg = (const float*)d_in[5];
    const float* bg = (const float*)d_in[6];

    const int N = in_sizes[0] / DF;        // 65536
    const int E = in_sizes[1] / 2;         // 2097152
    const int* rows = ei;
    const int* cols = ei + E;

    // FLOAT32 outputs, concatenated: x_new [32768*256] | new_edge_index [2*E] | batch_new [32768]
    float* outx = (float*)d_out;
    float* oute = outx + (size_t)NROWS * DF;       // 8388608
    float* outb = oute + (size_t)2 * E;            // +4194304

    // Scratch inside the x_new region (33.5 MB): 2 MB front (overwritten by gather_lo at the
    // end) + 256 KB rowinfo tail (consumed LDS-first by k_gather_hi). No d_ws usage.
    char* sb = (char*)d_out;
    float*     sc0      = (float*)(sb + 0);              //   0 .. 256K
    float*     xwg      = (float*)(sb + (1 << 18));      // 256K .. 512K
    long long* gcnq     = (long long*)(sb + (2 << 18));  // 512K .. 1M
    int*       degc     = (int*)(sb + (4 << 18));        //   1M .. 1.25M
    int*       node_map = (int*)(sb + (5 << 18));        // 1.25M .. 1.5M
    float*     score    = (float*)(sb + (6 << 18));      // 1.5M .. 1.75M
    int*       perm     = (int*)(sb + (7 << 18));        // 1.75M .. 1.875M
    int2*      rowinfo  = (int2*)(sb + (size_t)NROWS * DF * 4 - (size_t)NROWS * 8); // last 256K

    hipLaunchKernelGGL(k_init, dim3((N + 255) / 256), dim3(256), 0, stream, degc, gcnq, node_map, N);
    hipLaunchKernelGGL(k_dots, dim3(N / 4), dim3(256), 0, stream, x, w1, wg, sc0, xwg);
    hipLaunchKernelGGL(k_deg, dim3((E + 255) / 256), dim3(256), 0, stream, rows, cols, degc, E);
    hipLaunchKernelGGL(k_gcn, dim3((E + 255) / 256), dim3(256), 0, stream, rows, cols, degc, xwg, gcnq, E);
    hipLaunchKernelGGL(k_score, dim3((N + 255) / 256), dim3(256), 0, stream, sc0, gcnq, b1, bg, score, N);
    hipLaunchKernelGGL(k_topk, dim3(NG), dim3(512), 0, stream, score, perm, node_map);
    hipLaunchKernelGGL(k_prep, dim3(NROWS / 256), dim3(256), 0, stream, score, perm, rowinfo);
    hipLaunchKernelGGL(k_edges, dim3((E + 255) / 256), dim3(256), 0, stream, rows, cols, node_map, oute, E);
    hipLaunchKernelGGL(k_gather_lo, dim3(LO_ROWS / 4), dim3(256), 0, stream, x, rowinfo, outx, outb);
    hipLaunchKernelGGL(k_gather_hi, dim3(1), dim3(1024), 0, stream, x, rowinfo, outx, outb);
}

// Round 4
// 89.490 us; speedup vs baseline: 2.6120x; 2.6120x over previous
//
#include <hip/hip_runtime.h>

#define NPG 1024
#define NG 64
#define KKEEP 512
#define DF 256
#define NTOT (NG * NPG)        // 65536 nodes
#define NROWS (NG * KKEEP)     // 32768 kept rows
#define EPG 32768              // edges per graph (E / NG)
#define HI_ROWS 256
#define LO_ROWS (NROWS - HI_ROWS)  // 32512
#define FXS 1099511627776.0    // 2^40 fixed-point scale

// one wave per node: dot(x, w1) and dot(x, wg), f64 accumulate
__global__ void k_dots(const float* __restrict__ x, const float* __restrict__ w1,
                       const float* __restrict__ wg, float* __restrict__ sc0,
                       float* __restrict__ xwg) {
    int node = blockIdx.x * 4 + (threadIdx.x >> 6);
    int lane = threadIdx.x & 63;
    const float4 xv = *reinterpret_cast<const float4*>(x + (size_t)node * DF + lane * 4);
    const float4 av = *reinterpret_cast<const float4*>(w1 + lane * 4);
    const float4 bv = *reinterpret_cast<const float4*>(wg + lane * 4);
    double s1 = (double)xv.x * av.x + (double)xv.y * av.y + (double)xv.z * av.z + (double)xv.w * av.w;
    double s2 = (double)xv.x * bv.x + (double)xv.y * bv.y + (double)xv.z * bv.z + (double)xv.w * bv.w;
#pragma unroll
    for (int off = 32; off; off >>= 1) {
        s1 += __shfl_xor(s1, off);
        s2 += __shfl_xor(s2, off);
    }
    if (lane == 0) { sc0[node] = (float)s1; xwg[node] = (float)s2; }
}

// one block per graph: deg -> dis -> gcn scatter (LDS u64 fixed point) -> score -> top-k -> outputs
__global__ __launch_bounds__(1024) void k_fused(
        const int* __restrict__ rows, const int* __restrict__ cols,
        const float* __restrict__ sc0, const float* __restrict__ xwg,
        const float* __restrict__ b1, const float* __restrict__ bg,
        int* __restrict__ node_map, int2* __restrict__ rowinfo) {
    __shared__ int deg_l[NPG];
    __shared__ float xwg_l[NPG];
    __shared__ float dis_l[NPG];
    __shared__ unsigned long long gcn_l[NPG];
    __shared__ float score_l[NPG];
    __shared__ unsigned long long keys[NPG];

    const int g = blockIdx.x, t = threadIdx.x;
    const int nbase = g * NPG;

    deg_l[t] = 0;
    gcn_l[t] = 0;
    xwg_l[t] = xwg[nbase + t];
    node_map[nbase + t] = -1;
    __syncthreads();

    const int4* r4 = reinterpret_cast<const int4*>(rows + (size_t)g * EPG);
    const int4* c4 = reinterpret_cast<const int4*>(cols + (size_t)g * EPG);

    // pass 1: degree (self-loops removed)
    for (int i = t; i < EPG / 4; i += 1024) {
        int4 r = r4[i], c = c4[i];
        if (r.x != c.x) atomicAdd(&deg_l[c.x & (NPG - 1)], 1);
        if (r.y != c.y) atomicAdd(&deg_l[c.y & (NPG - 1)], 1);
        if (r.z != c.z) atomicAdd(&deg_l[c.z & (NPG - 1)], 1);
        if (r.w != c.w) atomicAdd(&deg_l[c.w & (NPG - 1)], 1);
    }
    __syncthreads();
    {
        int d = deg_l[t];
        dis_l[t] = (d > 0) ? (1.0f / sqrtf((float)d)) : 0.0f;
    }
    __syncthreads();

    // pass 2: gcn[c] += dis[r]*dis[c]*xwg[r]  (2^-40 fixed-point, order-free)
    for (int i = t; i < EPG / 4; i += 1024) {
        int4 r = r4[i], c = c4[i];
        int rl, cl; float term;
        rl = r.x & (NPG - 1); cl = c.x & (NPG - 1);
        if (r.x != c.x) { term = dis_l[rl] * dis_l[cl] * xwg_l[rl];
            atomicAdd(&gcn_l[cl], (unsigned long long)(long long)llrint((double)term * FXS)); }
        rl = r.y & (NPG - 1); cl = c.y & (NPG - 1);
        if (r.y != c.y) { term = dis_l[rl] * dis_l[cl] * xwg_l[rl];
            atomicAdd(&gcn_l[cl], (unsigned long long)(long long)llrint((double)term * FXS)); }
        rl = r.z & (NPG - 1); cl = c.z & (NPG - 1);
        if (r.z != c.z) { term = dis_l[rl] * dis_l[cl] * xwg_l[rl];
            atomicAdd(&gcn_l[cl], (unsigned long long)(long long)llrint((double)term * FXS)); }
        rl = r.w & (NPG - 1); cl = c.w & (NPG - 1);
        if (r.w != c.w) { term = dis_l[rl] * dis_l[cl] * xwg_l[rl];
            atomicAdd(&gcn_l[cl], (unsigned long long)(long long)llrint((double)term * FXS)); }
    }
    __syncthreads();

    // score + sort keys (score desc, index asc on ties -> matches lax.top_k order)
    {
        float s1 = sc0[nbase + t] + b1[0];
        float s2 = (float)((double)(long long)gcn_l[t] * (1.0 / FXS)) + bg[0];
        float s = 0.5f * s1 + 0.5f * s2;
        score_l[t] = s;
        unsigned u = __float_as_uint(s);
        u = (u & 0x80000000u) ? ~u : (u | 0x80000000u);
        keys[t] = ((unsigned long long)u << 32) | (unsigned long long)(0xFFFFFFFFu - (unsigned)t);
    }
    __syncthreads();

    // bitonic sort, descending
    for (int k = 2; k <= NPG; k <<= 1) {
        for (int j = k >> 1; j > 0; j >>= 1) {
            int ixj = t ^ j;
            if (ixj > t) {
                unsigned long long a = keys[t], b = keys[ixj];
                bool desc = ((t & k) == 0);
                if (desc ? (a < b) : (a > b)) { keys[t] = b; keys[ixj] = a; }
            }
            __syncthreads();
        }
    }

    if (t < KKEEP) {
        int idx = (int)(0xFFFFFFFFu - (unsigned)(keys[t] & 0xFFFFFFFFull)) & (NPG - 1);
        int gi = nbase + idx;
        int row = g * KKEEP + t;
        node_map[gi] = row;
        rowinfo[row] = make_int2(gi, __float_as_int(tanhf(score_l[idx])));
    }
}

// 4 edges/thread, int4/float4
__global__ void k_edges(const int* __restrict__ rows, const int* __restrict__ cols,
                        const int* __restrict__ node_map, float* __restrict__ oute, int E) {
    int i = blockIdx.x * blockDim.x + threadIdx.x;
    if (i >= E / 4) return;
    int4 r = reinterpret_cast<const int4*>(rows)[i];
    int4 c = reinterpret_cast<const int4*>(cols)[i];
    int ex = node_map[r.x & (NTOT - 1)], fx = node_map[c.x & (NTOT - 1)];
    int ey = node_map[r.y & (NTOT - 1)], fy = node_map[c.y & (NTOT - 1)];
    int ez = node_map[r.z & (NTOT - 1)], fz = node_map[c.z & (NTOT - 1)];
    int ew = node_map[r.w & (NTOT - 1)], fw = node_map[c.w & (NTOT - 1)];
    float4 orow, ocol;
    orow.x = (ex >= 0 && fx >= 0) ? (float)ex : -1.0f;  ocol.x = (ex >= 0 && fx >= 0) ? (float)fx : -1.0f;
    orow.y = (ey >= 0 && fy >= 0) ? (float)ey : -1.0f;  ocol.y = (ey >= 0 && fy >= 0) ? (float)fy : -1.0f;
    orow.z = (ez >= 0 && fz >= 0) ? (float)ez : -1.0f;  ocol.z = (ez >= 0 && fz >= 0) ? (float)fz : -1.0f;
    orow.w = (ew >= 0 && fw >= 0) ? (float)ew : -1.0f;  ocol.w = (ew >= 0 && fw >= 0) ? (float)fw : -1.0f;
    reinterpret_cast<float4*>(oute)[i] = orow;
    reinterpret_cast<float4*>(oute + (size_t)E)[i] = ocol;
}

// rows 0..32511: reads rowinfo (tail region, disjoint from rows written here)
__global__ void k_gather_lo(const float* __restrict__ x, const int2* __restrict__ rowinfo,
                            float* __restrict__ outx, float* __restrict__ outb) {
    int row = blockIdx.x * 4 + (threadIdx.x >> 6);
    int lane = threadIdx.x & 63;
    int2 ri = rowinfo[row];
    float tg = __int_as_float(ri.y);
    const float4 v = *reinterpret_cast<const float4*>(x + (size_t)(ri.x & (NTOT - 1)) * DF + lane * 4);
    float4 o;
    o.x = v.x * tg; o.y = v.y * tg; o.z = v.z * tg; o.w = v.w * tg;
    *reinterpret_cast<float4*>(outx + (size_t)row * DF + lane * 4) = o;
    if (lane == 0) outb[row] = (float)(row >> 9);
}

// rows 32512..32767: single workgroup; stage rowinfo in LDS before overwriting its region
__global__ __launch_bounds__(1024) void k_gather_hi(const float* __restrict__ x,
                                                    const int2* __restrict__ rowinfo,
                                                    float* __restrict__ outx,
                                                    float* __restrict__ outb) {
    __shared__ int2 info[HI_ROWS];
    int tid = threadIdx.x;
    if (tid < HI_ROWS) info[tid] = rowinfo[LO_ROWS + tid];
    __syncthreads();
    for (int it = tid; it < HI_ROWS * 64; it += 1024) {
        int rl = it >> 6, lane = it & 63;
        int row = LO_ROWS + rl;
        int2 ri = info[rl];
        float tg = __int_as_float(ri.y);
        const float4 v = *reinterpret_cast<const float4*>(x + (size_t)(ri.x & (NTOT - 1)) * DF + lane * 4);
        float4 o;
        o.x = v.x * tg; o.y = v.y * tg; o.z = v.z * tg; o.w = v.w * tg;
        *reinterpret_cast<float4*>(outx + (size_t)row * DF + lane * 4) = o;
        if (lane == 0) outb[row] = (float)(row >> 9);
    }
}

extern "C" void kernel_launch(void* const* d_in, const int* in_sizes, int n_in,
                              void* d_out, int out_size, void* d_ws, size_t ws_size,
                              hipStream_t stream) {
    const float* x = (const float*)d_in[0];
    const int* ei = (const int*)d_in[1];
    const float* w1 = (const float*)d_in[3];
    const float* b1 = (const float*)d_in[4];
    const float* wg = (const float*)d_in[5];
    const float* bg = (const float*)d_in[6];

    const int N = in_sizes[0] / DF;        // 65536
    const int E = in_sizes[1] / 2;         // 2097152
    const int* rows = ei;
    const int* cols = ei + E;

    // FLOAT32 outputs, concatenated: x_new [32768*256] | new_edge_index [2*E] | batch_new [32768]
    float* outx = (float*)d_out;
    float* oute = outx + (size_t)NROWS * DF;
    float* outb = oute + (size_t)2 * E;

    // Scratch inside x_new region: front (overwritten by k_gather_lo at the end)
    // + 256 KB rowinfo tail (consumed LDS-first by k_gather_hi). No d_ws usage.
    char* sb = (char*)d_out;
    float* sc0      = (float*)(sb + 0);              //   0 .. 256K
    float* xwg      = (float*)(sb + (1 << 18));      // 256K .. 512K
    int*   node_map = (int*)(sb + (2 << 18));        // 512K .. 768K
    int2*  rowinfo  = (int2*)(sb + (size_t)NROWS * DF * 4 - (size_t)NROWS * 8); // last 256K

    hipLaunchKernelGGL(k_dots, dim3(N / 4), dim3(256), 0, stream, x, w1, wg, sc0, xwg);
    hipLaunchKernelGGL(k_fused, dim3(NG), dim3(NPG), 0, stream,
                       rows, cols, sc0, xwg, b1, bg, node_map, rowinfo);
    hipLaunchKernelGGL(k_edges, dim3((E / 4 + 255) / 256), dim3(256), 0, stream,
                       rows, cols, node_map, oute, E);
    hipLaunchKernelGGL(k_gather_lo, dim3(LO_ROWS / 4), dim3(256), 0, stream, x, rowinfo, outx, outb);
    hipLaunchKernelGGL(k_gather_hi, dim3(1), dim3(1024), 0, stream, x, rowinfo, outx, outb);
}

// Round 5
// 67.564 us; speedup vs baseline: 3.4596x; 1.3245x over previous
//
#include <hip/hip_runtime.h>

#define NPG 1024
#define NG 64
#define KKEEP 512
#define DF 256
#define NTOT (NG * NPG)        // 65536 nodes
#define NROWS (NG * KKEEP)     // 32768 kept rows
#define EPG 32768              // edges per graph
#define NB 4                   // blocks per graph for deg/gcn passes
#define EPB (EPG / NB)         // 8192 edges per block
#define HI_ROWS 256
#define LO_ROWS (NROWS - HI_ROWS)
#define FXS 1099511627776.0    // 2^40 fixed-point scale

// one wave per node: dot(x, w1) and dot(x, wg), f64 accumulate
__global__ void k_dots(const float* __restrict__ x, const float* __restrict__ w1,
                       const float* __restrict__ wg, float* __restrict__ sc0,
                       float* __restrict__ xwg) {
    int node = blockIdx.x * 4 + (threadIdx.x >> 6);
    int lane = threadIdx.x & 63;
    const float4 xv = *reinterpret_cast<const float4*>(x + (size_t)node * DF + lane * 4);
    const float4 av = *reinterpret_cast<const float4*>(w1 + lane * 4);
    const float4 bv = *reinterpret_cast<const float4*>(wg + lane * 4);
    double s1 = (double)xv.x * av.x + (double)xv.y * av.y + (double)xv.z * av.z + (double)xv.w * av.w;
    double s2 = (double)xv.x * bv.x + (double)xv.y * bv.y + (double)xv.z * bv.z + (double)xv.w * bv.w;
#pragma unroll
    for (int off = 32; off; off >>= 1) {
        s1 += __shfl_xor(s1, off);
        s2 += __shfl_xor(s2, off);
    }
    if (lane == 0) { sc0[node] = (float)s1; xwg[node] = (float)s2; }
}

// 4 blocks per graph: LDS degree partials -> coalesced store (no atomics to global)
__global__ __launch_bounds__(1024) void k_deg(const int* __restrict__ rows,
                                              const int* __restrict__ cols,
                                              int* __restrict__ degp) {
    __shared__ int deg_l[NPG];
    const int t = threadIdx.x;
    const int g = blockIdx.x >> 2, b = blockIdx.x & 3;
    deg_l[t] = 0;
    __syncthreads();
    const int4* r4 = reinterpret_cast<const int4*>(rows + (size_t)g * EPG + b * EPB);
    const int4* c4 = reinterpret_cast<const int4*>(cols + (size_t)g * EPG + b * EPB);
    for (int i = t; i < EPB / 4; i += 1024) {
        int4 r = r4[i], c = c4[i];
        if (r.x != c.x) atomicAdd(&deg_l[c.x & (NPG - 1)], 1);
        if (r.y != c.y) atomicAdd(&deg_l[c.y & (NPG - 1)], 1);
        if (r.z != c.z) atomicAdd(&deg_l[c.z & (NPG - 1)], 1);
        if (r.w != c.w) atomicAdd(&deg_l[c.w & (NPG - 1)], 1);
    }
    __syncthreads();
    degp[(size_t)blockIdx.x * NPG + t] = deg_l[t];
}

// 4 blocks per graph: sum deg partials -> dis; LDS u64 fixed-point scatter; store partials
__global__ __launch_bounds__(1024) void k_gcn(const int* __restrict__ rows,
                                              const int* __restrict__ cols,
                                              const int* __restrict__ degp,
                                              const float* __restrict__ xwg,
                                              unsigned long long* __restrict__ gcnp) {
    __shared__ float dis_l[NPG];
    __shared__ float xwg_l[NPG];
    __shared__ unsigned long long gcn_l[NPG];
    const int t = threadIdx.x;
    const int g = blockIdx.x >> 2, b = blockIdx.x & 3;
    {
        int d = degp[(size_t)(g * NB + 0) * NPG + t] + degp[(size_t)(g * NB + 1) * NPG + t]
              + degp[(size_t)(g * NB + 2) * NPG + t] + degp[(size_t)(g * NB + 3) * NPG + t];
        dis_l[t] = (d > 0) ? (1.0f / sqrtf((float)d)) : 0.0f;
    }
    xwg_l[t] = xwg[g * NPG + t];
    gcn_l[t] = 0;
    __syncthreads();
    const int4* r4 = reinterpret_cast<const int4*>(rows + (size_t)g * EPG + b * EPB);
    const int4* c4 = reinterpret_cast<const int4*>(cols + (size_t)g * EPG + b * EPB);
    for (int i = t; i < EPB / 4; i += 1024) {
        int4 r = r4[i], c = c4[i];
        int rl, cl; float term;
        rl = r.x & (NPG - 1); cl = c.x & (NPG - 1);
        if (r.x != c.x) { term = dis_l[rl] * dis_l[cl] * xwg_l[rl];
            atomicAdd(&gcn_l[cl], (unsigned long long)(long long)llrint((double)term * FXS)); }
        rl = r.y & (NPG - 1); cl = c.y & (NPG - 1);
        if (r.y != c.y) { term = dis_l[rl] * dis_l[cl] * xwg_l[rl];
            atomicAdd(&gcn_l[cl], (unsigned long long)(long long)llrint((double)term * FXS)); }
        rl = r.z & (NPG - 1); cl = c.z & (NPG - 1);
        if (r.z != c.z) { term = dis_l[rl] * dis_l[cl] * xwg_l[rl];
            atomicAdd(&gcn_l[cl], (unsigned long long)(long long)llrint((double)term * FXS)); }
        rl = r.w & (NPG - 1); cl = c.w & (NPG - 1);
        if (r.w != c.w) { term = dis_l[rl] * dis_l[cl] * xwg_l[rl];
            atomicAdd(&gcn_l[cl], (unsigned long long)(long long)llrint((double)term * FXS)); }
    }
    __syncthreads();
    gcnp[(size_t)blockIdx.x * NPG + t] = gcn_l[t];
}

// one block per graph: score -> bitonic top-k -> node_map (ALL nodes) + rowinfo
__global__ __launch_bounds__(1024) void k_sort(const float* __restrict__ sc0,
                                               const unsigned long long* __restrict__ gcnp,
                                               const float* __restrict__ b1,
                                               const float* __restrict__ bg,
                                               int* __restrict__ node_map,
                                               int2* __restrict__ rowinfo) {
    __shared__ unsigned long long keys[NPG];
    __shared__ float score_l[NPG];
    const int g = blockIdx.x, t = threadIdx.x;
    const int nbase = g * NPG;
    {
        long long q = (long long)(gcnp[(size_t)(g * NB + 0) * NPG + t]
                                + gcnp[(size_t)(g * NB + 1) * NPG + t]
                                + gcnp[(size_t)(g * NB + 2) * NPG + t]
                                + gcnp[(size_t)(g * NB + 3) * NPG + t]);
        float s2 = (float)((double)q * (1.0 / FXS)) + bg[0];
        float s1 = sc0[nbase + t] + b1[0];
        float s = 0.5f * s1 + 0.5f * s2;
        score_l[t] = s;
        unsigned u = __float_as_uint(s);
        u = (u & 0x80000000u) ? ~u : (u | 0x80000000u);
        keys[t] = ((unsigned long long)u << 32) | (unsigned long long)(0xFFFFFFFFu - (unsigned)t);
    }
    __syncthreads();
    for (int k = 2; k <= NPG; k <<= 1) {
        for (int j = k >> 1; j > 0; j >>= 1) {
            int ixj = t ^ j;
            if (ixj > t) {
                unsigned long long a = keys[t], b = keys[ixj];
                bool desc = ((t & k) == 0);
                if (desc ? (a < b) : (a > b)) { keys[t] = b; keys[ixj] = a; }
            }
            __syncthreads();
        }
    }
    int idx = (int)(0xFFFFFFFFu - (unsigned)(keys[t] & 0xFFFFFFFFull)) & (NPG - 1);
    if (t < KKEEP) {
        int row = g * KKEEP + t;
        node_map[nbase + idx] = row;
        rowinfo[row] = make_int2(nbase + idx, __float_as_int(tanhf(score_l[idx])));
    } else {
        node_map[nbase + idx] = -1;
    }
}

// 4 edges/thread, int4/float4
__global__ void k_edges(const int* __restrict__ rows, const int* __restrict__ cols,
                        const int* __restrict__ node_map, float* __restrict__ oute, int E) {
    int i = blockIdx.x * blockDim.x + threadIdx.x;
    if (i >= E / 4) return;
    int4 r = reinterpret_cast<const int4*>(rows)[i];
    int4 c = reinterpret_cast<const int4*>(cols)[i];
    int ex = node_map[r.x & (NTOT - 1)], fx = node_map[c.x & (NTOT - 1)];
    int ey = node_map[r.y & (NTOT - 1)], fy = node_map[c.y & (NTOT - 1)];
    int ez = node_map[r.z & (NTOT - 1)], fz = node_map[c.z & (NTOT - 1)];
    int ew = node_map[r.w & (NTOT - 1)], fw = node_map[c.w & (NTOT - 1)];
    float4 orow, ocol;
    orow.x = (ex >= 0 && fx >= 0) ? (float)ex : -1.0f;  ocol.x = (ex >= 0 && fx >= 0) ? (float)fx : -1.0f;
    orow.y = (ey >= 0 && fy >= 0) ? (float)ey : -1.0f;  ocol.y = (ey >= 0 && fy >= 0) ? (float)fy : -1.0f;
    orow.z = (ez >= 0 && fz >= 0) ? (float)ez : -1.0f;  ocol.z = (ez >= 0 && fz >= 0) ? (float)fz : -1.0f;
    orow.w = (ew >= 0 && fw >= 0) ? (float)ew : -1.0f;  ocol.w = (ew >= 0 && fw >= 0) ? (float)fw : -1.0f;
    reinterpret_cast<float4*>(oute)[i] = orow;
    reinterpret_cast<float4*>(oute + (size_t)E)[i] = ocol;
}

// gather rows [row0, row0+nrows): one wave per row
__global__ void k_gather(const float* __restrict__ x, const int2* __restrict__ rowinfo,
                         float* __restrict__ outx, float* __restrict__ outb, int row0) {
    int row = row0 + blockIdx.x * 4 + (threadIdx.x >> 6);
    int lane = threadIdx.x & 63;
    int2 ri = rowinfo[row];
    float tg = __int_as_float(ri.y);
    const float4 v = *reinterpret_cast<const float4*>(x + (size_t)(ri.x & (NTOT - 1)) * DF + lane * 4);
    float4 o;
    o.x = v.x * tg; o.y = v.y * tg; o.z = v.z * tg; o.w = v.w * tg;
    *reinterpret_cast<float4*>(outx + (size_t)row * DF + lane * 4) = o;
    if (lane == 0) outb[row] = (float)(row >> 9);
}

// fallback tail gather: single workgroup, stages rowinfo tail in LDS before overwriting it
__global__ __launch_bounds__(1024) void k_gather_hi(const float* __restrict__ x,
                                                    const int2* __restrict__ rowinfo,
                                                    float* __restrict__ outx,
                                                    float* __restrict__ outb) {
    __shared__ int2 info[HI_ROWS];
    int tid = threadIdx.x;
    if (tid < HI_ROWS) info[tid] = rowinfo[LO_ROWS + tid];
    __syncthreads();
    for (int it = tid; it < HI_ROWS * 64; it += 1024) {
        int rl = it >> 6, lane = it & 63;
        int row = LO_ROWS + rl;
        int2 ri = info[rl];
        float tg = __int_as_float(ri.y);
        const float4 v = *reinterpret_cast<const float4*>(x + (size_t)(ri.x & (NTOT - 1)) * DF + lane * 4);
        float4 o;
        o.x = v.x * tg; o.y = v.y * tg; o.z = v.z * tg; o.w = v.w * tg;
        *reinterpret_cast<float4*>(outx + (size_t)row * DF + lane * 4) = o;
        if (lane == 0) outb[row] = (float)(row >> 9);
    }
}

extern "C" void kernel_launch(void* const* d_in, const int* in_sizes, int n_in,
                              void* d_out, int out_size, void* d_ws, size_t ws_size,
                              hipStream_t stream) {
    const float* x = (const float*)d_in[0];
    const int* ei = (const int*)d_in[1];
    const float* w1 = (const float*)d_in[3];
    const float* b1 = (const float*)d_in[4];
    const float* wg = (const float*)d_in[5];
    const float* bg = (const float*)d_in[6];

    const int N = in_sizes[0] / DF;        // 65536
    const int E = in_sizes[1] / 2;         // 2097152
    const int* rows = ei;
    const int* cols = ei + E;

    // FLOAT32 outputs: x_new [32768*256] | new_edge_index [2*E] | batch_new [32768]
    float* outx = (float*)d_out;
    float* oute = outx + (size_t)NROWS * DF;
    float* outb = oute + (size_t)2 * E;

    // Large scratch in the front of the x_new region (all consumed before k_gather
    // overwrites it): sc0 | xwg | degp (1MB) | gcnp (2MB) -> 3.5 MB total.
    char* sb = (char*)d_out;
    float*              sc0  = (float*)(sb + 0);                    //   0 .. 256K
    float*              xwg  = (float*)(sb + (1 << 18));            // 256K .. 512K
    int*                degp = (int*)(sb + (2 << 18));              // 512K .. 1.5M
    unsigned long long* gcnp = (unsigned long long*)(sb + (6 << 18)); // 1.5M .. 3.5M

    // node_map + rowinfo (512 KB) live in d_ws when it's big enough (no aliasing ->
    // one uniform gather). Fallback: alias into d_out with the hi/lo gather split.
    bool use_ws = (ws_size >= (size_t)(NTOT * 4 + NROWS * 8));
    int*  node_map;
    int2* rowinfo;
    if (use_ws) {
        node_map = (int*)d_ws;
        rowinfo  = (int2*)((char*)d_ws + (size_t)NTOT * 4);
    } else {
        node_map = (int*)(sb + (14 << 18));                                   // 3.5M .. 3.75M
        rowinfo  = (int2*)(sb + (size_t)NROWS * DF * 4 - (size_t)NROWS * 8);  // last 256K
    }

    hipLaunchKernelGGL(k_dots, dim3(N / 4), dim3(256), 0, stream, x, w1, wg, sc0, xwg);
    hipLaunchKernelGGL(k_deg, dim3(NG * NB), dim3(1024), 0, stream, rows, cols, degp);
    hipLaunchKernelGGL(k_gcn, dim3(NG * NB), dim3(1024), 0, stream, rows, cols, degp, xwg, gcnp);
    hipLaunchKernelGGL(k_sort, dim3(NG), dim3(1024), 0, stream, sc0, gcnp, b1, bg, node_map, rowinfo);
    hipLaunchKernelGGL(k_edges, dim3((E / 4 + 255) / 256), dim3(256), 0, stream,
                       rows, cols, node_map, oute, E);
    if (use_ws) {
        hipLaunchKernelGGL(k_gather, dim3(NROWS / 4), dim3(256), 0, stream, x, rowinfo, outx, outb, 0);
    } else {
        hipLaunchKernelGGL(k_gather, dim3(LO_ROWS / 4), dim3(256), 0, stream, x, rowinfo, outx, outb, 0);
        hipLaunchKernelGGL(k_gather_hi, dim3(1), dim3(1024), 0, stream, x, rowinfo, outx, outb);
    }
}

// Round 6
// 60.096 us; speedup vs baseline: 3.8895x; 1.1243x over previous
//
#include <hip/hip_runtime.h>

#define NPG 1024
#define NG 64
#define KKEEP 512
#define DF 256
#define NTOT (NG * NPG)        // 65536 nodes
#define NROWS (NG * KKEEP)     // 32768 kept rows
#define EPG 32768              // edges per graph
#define NB 8                   // blocks per graph for deg/gcn passes
#define EPB (EPG / NB)         // 4096 edges per block
#define HI_ROWS 256
#define LO_ROWS (NROWS - HI_ROWS)
#define FXS 1099511627776.0    // 2^40 fixed-point scale

// in-register bitonic compare-exchange via wave shuffle (j <= 32)
__device__ __forceinline__ unsigned long long cex(unsigned long long a, int t, int k, int j) {
    unsigned long long b = __shfl_xor(a, j, 64);
    bool lower = ((t & j) == 0);
    bool desc  = ((t & k) == 0);
    unsigned long long mn = a < b ? a : b;
    unsigned long long mx = a < b ? b : a;
    return (desc == lower) ? mx : mn;
}

// fused: blocks [0, NTOT/4) = dots (wave per node); blocks [NTOT/4, +NG*NB) = degree partials
__global__ __launch_bounds__(256) void k_front(const float* __restrict__ x,
                                               const float* __restrict__ w1,
                                               const float* __restrict__ wg,
                                               const int* __restrict__ rows,
                                               const int* __restrict__ cols,
                                               float* __restrict__ sc0,
                                               float* __restrict__ xwg,
                                               int* __restrict__ degp) {
    __shared__ int deg_l[NPG];
    const int b = blockIdx.x;
    const int t = threadIdx.x;
    if (b < NTOT / 4) {
        int node = b * 4 + (t >> 6);
        int lane = t & 63;
        const float4 xv = *reinterpret_cast<const float4*>(x + (size_t)node * DF + lane * 4);
        const float4 av = *reinterpret_cast<const float4*>(w1 + lane * 4);
        const float4 bv = *reinterpret_cast<const float4*>(wg + lane * 4);
        double s1 = (double)xv.x * av.x + (double)xv.y * av.y + (double)xv.z * av.z + (double)xv.w * av.w;
        double s2 = (double)xv.x * bv.x + (double)xv.y * bv.y + (double)xv.z * bv.z + (double)xv.w * bv.w;
#pragma unroll
        for (int off = 32; off; off >>= 1) {
            s1 += __shfl_xor(s1, off);
            s2 += __shfl_xor(s2, off);
        }
        if (lane == 0) { sc0[node] = (float)s1; xwg[node] = (float)s2; }
    } else {
        const int bb = b - NTOT / 4;            // 0 .. NG*NB-1
        const int g = bb >> 3, sub = bb & 7;
        deg_l[t] = 0; deg_l[t + 256] = 0; deg_l[t + 512] = 0; deg_l[t + 768] = 0;
        __syncthreads();
        const int4* r4 = reinterpret_cast<const int4*>(rows + (size_t)g * EPG + sub * EPB);
        const int4* c4 = reinterpret_cast<const int4*>(cols + (size_t)g * EPG + sub * EPB);
        for (int i = t; i < EPB / 4; i += 256) {
            int4 r = r4[i], c = c4[i];
            if (r.x != c.x) atomicAdd(&deg_l[c.x & (NPG - 1)], 1);
            if (r.y != c.y) atomicAdd(&deg_l[c.y & (NPG - 1)], 1);
            if (r.z != c.z) atomicAdd(&deg_l[c.z & (NPG - 1)], 1);
            if (r.w != c.w) atomicAdd(&deg_l[c.w & (NPG - 1)], 1);
        }
        __syncthreads();
        int* dst = degp + (size_t)bb * NPG;
        dst[t] = deg_l[t]; dst[t + 256] = deg_l[t + 256];
        dst[t + 512] = deg_l[t + 512]; dst[t + 768] = deg_l[t + 768];
    }
}

// NB blocks/graph: sum deg partials -> dis; LDS u64 fixed-point scatter; store partials
__global__ __launch_bounds__(1024) void k_gcn(const int* __restrict__ rows,
                                              const int* __restrict__ cols,
                                              const int* __restrict__ degp,
                                              const float* __restrict__ xwg,
                                              unsigned long long* __restrict__ gcnp) {
    __shared__ float dis_l[NPG];
    __shared__ float xwg_l[NPG];
    __shared__ unsigned long long gcn_l[NPG];
    const int t = threadIdx.x;
    const int g = blockIdx.x >> 3, sub = blockIdx.x & 7;
    {
        int d = 0;
#pragma unroll
        for (int p = 0; p < NB; ++p) d += degp[(size_t)(g * NB + p) * NPG + t];
        dis_l[t] = (d > 0) ? (1.0f / sqrtf((float)d)) : 0.0f;
    }
    xwg_l[t] = xwg[g * NPG + t];
    gcn_l[t] = 0;
    __syncthreads();
    const int4* r4 = reinterpret_cast<const int4*>(rows + (size_t)g * EPG + sub * EPB);
    const int4* c4 = reinterpret_cast<const int4*>(cols + (size_t)g * EPG + sub * EPB);
    for (int i = t; i < EPB / 4; i += 1024) {
        int4 r = r4[i], c = c4[i];
        int rl, cl; float term;
        rl = r.x & (NPG - 1); cl = c.x & (NPG - 1);
        if (r.x != c.x) { term = dis_l[rl] * dis_l[cl] * xwg_l[rl];
            atomicAdd(&gcn_l[cl], (unsigned long long)(long long)llrint((double)term * FXS)); }
        rl = r.y & (NPG - 1); cl = c.y & (NPG - 1);
        if (r.y != c.y) { term = dis_l[rl] * dis_l[cl] * xwg_l[rl];
            atomicAdd(&gcn_l[cl], (unsigned long long)(long long)llrint((double)term * FXS)); }
        rl = r.z & (NPG - 1); cl = c.z & (NPG - 1);
        if (r.z != c.z) { term = dis_l[rl] * dis_l[cl] * xwg_l[rl];
            atomicAdd(&gcn_l[cl], (unsigned long long)(long long)llrint((double)term * FXS)); }
        rl = r.w & (NPG - 1); cl = c.w & (NPG - 1);
        if (r.w != c.w) { term = dis_l[rl] * dis_l[cl] * xwg_l[rl];
            atomicAdd(&gcn_l[cl], (unsigned long long)(long long)llrint((double)term * FXS)); }
    }
    __syncthreads();
    gcnp[(size_t)blockIdx.x * NPG + t] = gcn_l[t];
}

// one block per graph: score -> hybrid bitonic (shuffle for j<=32, LDS for j>=64) -> outputs
__global__ __launch_bounds__(1024) void k_sort(const float* __restrict__ sc0,
                                               const unsigned long long* __restrict__ gcnp,
                                               const float* __restrict__ b1,
                                               const float* __restrict__ bg,
                                               int* __restrict__ node_map,
                                               int2* __restrict__ rowinfo) {
    __shared__ unsigned long long keys[NPG];
    __shared__ float score_l[NPG];
    const int g = blockIdx.x, t = threadIdx.x;
    const int nbase = g * NPG;
    unsigned long long key;
    {
        long long q = 0;
#pragma unroll
        for (int p = 0; p < NB; ++p) q += (long long)gcnp[(size_t)(g * NB + p) * NPG + t];
        float s2 = (float)((double)q * (1.0 / FXS)) + bg[0];
        float s1 = sc0[nbase + t] + b1[0];
        float s = 0.5f * s1 + 0.5f * s2;
        score_l[t] = s;
        unsigned u = __float_as_uint(s);
        u = (u & 0x80000000u) ? ~u : (u | 0x80000000u);
        key = ((unsigned long long)u << 32) | (unsigned long long)(0xFFFFFFFFu - (unsigned)t);
    }
    // k = 2..64: fully intra-wave, registers + shuffles, zero barriers
#pragma unroll
    for (int k = 2; k <= 64; k <<= 1)
        for (int j = k >> 1; j > 0; j >>= 1)
            key = cex(key, t, k, j);
    keys[t] = key;
    __syncthreads();
    // k = 128..1024: LDS steps for j>=64 (single-writer pairs), shuffle tail for j<=32
    for (int k = 128; k <= NPG; k <<= 1) {
        for (int j = k >> 1; j >= 64; j >>= 1) {
            int ixj = t ^ j;
            if (ixj > t) {
                unsigned long long a = keys[t], b = keys[ixj];
                bool desc = ((t & k) == 0);
                if (desc ? (a < b) : (a > b)) { keys[t] = b; keys[ixj] = a; }
            }
            __syncthreads();
        }
        key = keys[t];
#pragma unroll
        for (int j = 32; j > 0; j >>= 1)
            key = cex(key, t, k, j);
        if (k < NPG) { keys[t] = key; __syncthreads(); }
    }
    // key register now holds the element at sorted position t (descending)
    int idx = (int)(0xFFFFFFFFu - (unsigned)(key & 0xFFFFFFFFull)) & (NPG - 1);
    if (t < KKEEP) {
        int row = g * KKEEP + t;
        node_map[nbase + idx] = row;
        rowinfo[row] = make_int2(nbase + idx, __float_as_int(tanhf(score_l[idx])));
    } else {
        node_map[nbase + idx] = -1;
    }
}

// fused output: blocks [0, NROWS/4) = gather (wave per row); rest = edge relabel (int4/float4)
__global__ __launch_bounds__(256) void k_out(const float* __restrict__ x,
                                             const int* __restrict__ rows,
                                             const int* __restrict__ cols,
                                             const int* __restrict__ node_map,
                                             const int2* __restrict__ rowinfo,
                                             float* __restrict__ outx,
                                             float* __restrict__ oute,
                                             float* __restrict__ outb, int E) {
    const int b = blockIdx.x;
    const int t = threadIdx.x;
    if (b < NROWS / 4) {
        int row = b * 4 + (t >> 6);
        int lane = t & 63;
        int2 ri = rowinfo[row];
        float tg = __int_as_float(ri.y);
        const float4 v = *reinterpret_cast<const float4*>(x + (size_t)(ri.x & (NTOT - 1)) * DF + lane * 4);
        float4 o;
        o.x = v.x * tg; o.y = v.y * tg; o.z = v.z * tg; o.w = v.w * tg;
        *reinterpret_cast<float4*>(outx + (size_t)row * DF + lane * 4) = o;
        if (lane == 0) outb[row] = (float)(row >> 9);
    } else {
        int i = (b - NROWS / 4) * 256 + t;
        if (i < E / 4) {
            int4 r = reinterpret_cast<const int4*>(rows)[i];
            int4 c = reinterpret_cast<const int4*>(cols)[i];
            int ex = node_map[r.x & (NTOT - 1)], fx = node_map[c.x & (NTOT - 1)];
            int ey = node_map[r.y & (NTOT - 1)], fy = node_map[c.y & (NTOT - 1)];
            int ez = node_map[r.z & (NTOT - 1)], fz = node_map[c.z & (NTOT - 1)];
            int ew = node_map[r.w & (NTOT - 1)], fw = node_map[c.w & (NTOT - 1)];
            float4 orow, ocol;
            orow.x = (ex >= 0 && fx >= 0) ? (float)ex : -1.0f;  ocol.x = (ex >= 0 && fx >= 0) ? (float)fx : -1.0f;
            orow.y = (ey >= 0 && fy >= 0) ? (float)ey : -1.0f;  ocol.y = (ey >= 0 && fy >= 0) ? (float)fy : -1.0f;
            orow.z = (ez >= 0 && fz >= 0) ? (float)ez : -1.0f;  ocol.z = (ez >= 0 && fz >= 0) ? (float)fz : -1.0f;
            orow.w = (ew >= 0 && fw >= 0) ? (float)ew : -1.0f;  ocol.w = (ew >= 0 && fw >= 0) ? (float)fw : -1.0f;
            reinterpret_cast<float4*>(oute)[i] = orow;
            reinterpret_cast<float4*>(oute + (size_t)E)[i] = ocol;
        }
    }
}

// ---- fallback-path kernels (scratch aliased into d_out; edges must precede gather) ----
__global__ void k_edges(const int* __restrict__ rows, const int* __restrict__ cols,
                        const int* __restrict__ node_map, float* __restrict__ oute, int E) {
    int i = blockIdx.x * blockDim.x + threadIdx.x;
    if (i >= E / 4) return;
    int4 r = reinterpret_cast<const int4*>(rows)[i];
    int4 c = reinterpret_cast<const int4*>(cols)[i];
    int ex = node_map[r.x & (NTOT - 1)], fx = node_map[c.x & (NTOT - 1)];
    int ey = node_map[r.y & (NTOT - 1)], fy = node_map[c.y & (NTOT - 1)];
    int ez = node_map[r.z & (NTOT - 1)], fz = node_map[c.z & (NTOT - 1)];
    int ew = node_map[r.w & (NTOT - 1)], fw = node_map[c.w & (NTOT - 1)];
    float4 orow, ocol;
    orow.x = (ex >= 0 && fx >= 0) ? (float)ex : -1.0f;  ocol.x = (ex >= 0 && fx >= 0) ? (float)fx : -1.0f;
    orow.y = (ey >= 0 && fy >= 0) ? (float)ey : -1.0f;  ocol.y = (ey >= 0 && fy >= 0) ? (float)fy : -1.0f;
    orow.z = (ez >= 0 && fz >= 0) ? (float)ez : -1.0f;  ocol.z = (ez >= 0 && fz >= 0) ? (float)fz : -1.0f;
    orow.w = (ew >= 0 && fw >= 0) ? (float)ew : -1.0f;  ocol.w = (ew >= 0 && fw >= 0) ? (float)fw : -1.0f;
    reinterpret_cast<float4*>(oute)[i] = orow;
    reinterpret_cast<float4*>(oute + (size_t)E)[i] = ocol;
}

__global__ void k_gather(const float* __restrict__ x, const int2* __restrict__ rowinfo,
                         float* __restrict__ outx, float* __restrict__ outb) {
    int row = blockIdx.x * 4 + (threadIdx.x >> 6);
    int lane = threadIdx.x & 63;
    int2 ri = rowinfo[row];
    float tg = __int_as_float(ri.y);
    const float4 v = *reinterpret_cast<const float4*>(x + (size_t)(ri.x & (NTOT - 1)) * DF + lane * 4);
    float4 o;
    o.x = v.x * tg; o.y = v.y * tg; o.z = v.z * tg; o.w = v.w * tg;
    *reinterpret_cast<float4*>(outx + (size_t)row * DF + lane * 4) = o;
    if (lane == 0) outb[row] = (float)(row >> 9);
}

__global__ __launch_bounds__(1024) void k_gather_hi(const float* __restrict__ x,
                                                    const int2* __restrict__ rowinfo,
                                                    float* __restrict__ outx,
                                                    float* __restrict__ outb) {
    __shared__ int2 info[HI_ROWS];
    int tid = threadIdx.x;
    if (tid < HI_ROWS) info[tid] = rowinfo[LO_ROWS + tid];
    __syncthreads();
    for (int it = tid; it < HI_ROWS * 64; it += 1024) {
        int rl = it >> 6, lane = it & 63;
        int row = LO_ROWS + rl;
        int2 ri = info[rl];
        float tg = __int_as_float(ri.y);
        const float4 v = *reinterpret_cast<const float4*>(x + (size_t)(ri.x & (NTOT - 1)) * DF + lane * 4);
        float4 o;
        o.x = v.x * tg; o.y = v.y * tg; o.z = v.z * tg; o.w = v.w * tg;
        *reinterpret_cast<float4*>(outx + (size_t)row * DF + lane * 4) = o;
        if (lane == 0) outb[row] = (float)(row >> 9);
    }
}

extern "C" void kernel_launch(void* const* d_in, const int* in_sizes, int n_in,
                              void* d_out, int out_size, void* d_ws, size_t ws_size,
                              hipStream_t stream) {
    const float* x = (const float*)d_in[0];
    const int* ei = (const int*)d_in[1];
    const float* w1 = (const float*)d_in[3];
    const float* b1 = (const float*)d_in[4];
    const float* wg = (const float*)d_in[5];
    const float* bg = (const float*)d_in[6];

    const int N = in_sizes[0] / DF;        // 65536
    const int E = in_sizes[1] / 2;         // 2097152
    const int* rows = ei;
    const int* cols = ei + E;

    // FLOAT32 outputs: x_new [32768*256] | new_edge_index [2*E] | batch_new [32768]
    float* outx = (float*)d_out;
    float* oute = outx + (size_t)NROWS * DF;
    float* outb = oute + (size_t)2 * E;

    // Scratch in the front of the x_new region (all consumed before gather overwrites it):
    // sc0 256K | xwg 256K | degp 2M | gcnp 4M  -> 6.5 MB total.
    char* sb = (char*)d_out;
    float*              sc0  = (float*)(sb + 0);                      //   0 .. 256K
    float*              xwg  = (float*)(sb + (1 << 18));              // 256K .. 512K
    int*                degp = (int*)(sb + (2 << 18));                // 512K .. 2.5M
    unsigned long long* gcnp = (unsigned long long*)(sb + (10 << 18)); // 2.5M .. 6.5M

    // node_map + rowinfo in d_ws when available (enables fused k_out); else alias d_out.
    bool use_ws = (ws_size >= (size_t)(NTOT * 4 + NROWS * 8));
    int*  node_map;
    int2* rowinfo;
    if (use_ws) {
        node_map = (int*)d_ws;
        rowinfo  = (int2*)((char*)d_ws + (size_t)NTOT * 4);
    } else {
        node_map = (int*)(sb + (26 << 18));                                   // 6.5M .. 6.75M
        rowinfo  = (int2*)(sb + (size_t)NROWS * DF * 4 - (size_t)NROWS * 8);  // last 256K
    }

    hipLaunchKernelGGL(k_front, dim3(NTOT / 4 + NG * NB), dim3(256), 0, stream,
                       x, w1, wg, rows, cols, sc0, xwg, degp);
    hipLaunchKernelGGL(k_gcn, dim3(NG * NB), dim3(1024), 0, stream, rows, cols, degp, xwg, gcnp);
    hipLaunchKernelGGL(k_sort, dim3(NG), dim3(1024), 0, stream, sc0, gcnp, b1, bg, node_map, rowinfo);
    if (use_ws) {
        hipLaunchKernelGGL(k_out, dim3(NROWS / 4 + E / 4 / 256), dim3(256), 0, stream,
                           x, rows, cols, node_map, rowinfo, outx, oute, outb, E);
    } else {
        hipLaunchKernelGGL(k_edges, dim3((E / 4 + 255) / 256), dim3(256), 0, stream,
                           rows, cols, node_map, oute, E);
        hipLaunchKernelGGL(k_gather, dim3(LO_ROWS / 4), dim3(256), 0, stream, x, rowinfo, outx, outb);
        hipLaunchKernelGGL(k_gather_hi, dim3(1), dim3(1024), 0, stream, x, rowinfo, outx, outb);
    }
}